// Round 2
// baseline (589.140 us; speedup 1.0000x reference)
//
#include <hip/hip_runtime.h>

#define N_NODES 50000
#define E_EDGES 800000
#define IN_DIM  128
#define HID_DIM 256
#define OUT_DIM 64
#define G_GRAPHS 500

__device__ __forceinline__ float bf2f(unsigned short u) {
  union { unsigned int i; float f; } c; c.i = ((unsigned int)u) << 16; return c.f;
}
__device__ __forceinline__ unsigned short f2bf(float f) {
  union { float f; unsigned int i; } c; c.f = f;
  unsigned int x = c.i;
  x += 0x7FFFu + ((x >> 16) & 1u);   // round-to-nearest-even
  return (unsigned short)(x >> 16);
}

// ---------------- CSR build ----------------

__global__ void count_deg(const int* __restrict__ dst, int* __restrict__ deg) {
  const int e = blockIdx.x * blockDim.x + threadIdx.x;
  if (e < E_EDGES) atomicAdd(&deg[dst[e]], 1);
}

// exclusive scan over N_NODES degrees -> indptr[0..N], single block of 256
__global__ __launch_bounds__(256) void scan_indptr(const int* __restrict__ deg,
                                                   int* __restrict__ indptr) {
  __shared__ int sums[256];
  const int tid = threadIdx.x;
  const int CH = (N_NODES + 255) / 256;  // 196
  const int lo = tid * CH;
  const int hi = (lo + CH < N_NODES) ? (lo + CH) : N_NODES;
  int s = 0;
  for (int i = lo; i < hi; ++i) s += deg[i];
  sums[tid] = s;
  __syncthreads();
  for (int off = 1; off < 256; off <<= 1) {
    int t = (tid >= off) ? sums[tid - off] : 0;
    __syncthreads();
    sums[tid] += t;
    __syncthreads();
  }
  int run = (tid == 0) ? 0 : sums[tid - 1];
  for (int i = lo; i < hi; ++i) { indptr[i] = run; run += deg[i]; }
  if (tid == 255) indptr[N_NODES] = run;
}

__global__ void fill_csr(const int* __restrict__ src, const int* __restrict__ dst,
                         const int* __restrict__ indptr, int* __restrict__ cursor,
                         int* __restrict__ srcs) {
  const int e = blockIdx.x * blockDim.x + threadIdx.x;
  if (e >= E_EDGES) return;
  const int d = dst[e];
  const int pos = atomicAdd(&cursor[d], 1);
  srcs[indptr[d] + pos] = src[e];
}

__global__ void build_first(const int* __restrict__ batch, int* __restrict__ first_node) {
  const int i = blockIdx.x * blockDim.x + threadIdx.x;
  if (i >= N_NODES) return;
  if (i == 0 || batch[i] != batch[i - 1]) first_node[batch[i]] = i;
}

// ---------------- Fused aggregate + GEMM + bias + L2norm + leaky ----------------
// Block: 256 threads = 4 waves, 16 nodes, 256 outputs.
// Phase 1 (aggregate): wave w gathers neighbors for nodes node0+w*4..+3.
//   Lane owns VPT=K/64 channels; neighbor row loads are coalesced
//   (float2 for K=128 f32 input, ushort4 for K=256 bf16 input); fp32 reg acc;
//   one transposed LDS store per node at the end.
// Phase 2 (GEMM): thread (tm=lane, tn=wave) owns 4x4 micro-tile: nodes
//   tn*4..+3 (its own wave's nodes -> norm reduction is pure wave shuffle),
//   outputs tm*4..+3. LDS read is wave-broadcast (conflict-free); W read is
//   float4/lane coalesced.

template<int K, typename TIN>
__global__ __launch_bounds__(256) void fused_layer(
    const TIN* __restrict__ H,                // [N, K]  (float or bf16-as-ushort)
    const int* __restrict__ indptr, const int* __restrict__ srcs,
    const float* __restrict__ W,              // [K, 256] f32
    const float* __restrict__ bias,           // [256] f32
    unsigned short* __restrict__ Hout,        // [N, 256] bf16
    int n_nodes)
{
  constexpr int M = 256;
  constexpr int TN = 16;
  constexpr int VPT = K / 64;                 // 2 (K=128) or 4 (K=256)
  constexpr int LDA = TN + 4;                 // pad to 20 -> float4 rows stay 16B aligned
  __shared__ float a_s[K][LDA];
  const int tid = threadIdx.x;
  const int lane = tid & 63;
  const int wv = tid >> 6;
  const int node0 = blockIdx.x * TN;

  // ---- Phase 1: aggregate ----
  for (int i = 0; i < 4; ++i) {
    const int nn = wv * 4 + i;
    const int node = node0 + nn;
    float acc[VPT];
#pragma unroll
    for (int j = 0; j < VPT; ++j) acc[j] = 0.f;
    if (node < n_nodes) {
      const int p1 = indptr[node + 1];
      for (int p = indptr[node]; p < p1; ++p) {
        const int s = srcs[p];
        if constexpr (sizeof(TIN) == 4) {     // fp32 input, VPT == 2
          const float2 u = *(const float2*)(H + (size_t)s * K + lane * VPT);
          acc[0] += u.x; acc[1] += u.y;
        } else {                              // bf16 input, VPT == 4
          const ushort4 u = *(const ushort4*)((const unsigned short*)H + (size_t)s * K + lane * VPT);
          acc[0] += bf2f(u.x); acc[1] += bf2f(u.y); acc[2] += bf2f(u.z); acc[3] += bf2f(u.w);
        }
      }
    }
#pragma unroll
    for (int j = 0; j < VPT; ++j) a_s[lane * VPT + j][nn] = acc[j];
  }
  __syncthreads();

  // ---- Phase 2: GEMM + bias + normalize + leaky ----
  const int tm = lane, tn = wv;
  float acc[4][4];
#pragma unroll
  for (int i = 0; i < 4; ++i)
#pragma unroll
    for (int j = 0; j < 4; ++j) acc[i][j] = 0.f;

  const float* Wp = W + (size_t)tm * 4;
#pragma unroll 4
  for (int k = 0; k < K; ++k) {
    const float4 av = *(const float4*)&a_s[k][tn * 4];
    const float4 wvv = *(const float4*)(Wp + (size_t)k * M);
    acc[0][0] += av.x * wvv.x; acc[0][1] += av.x * wvv.y; acc[0][2] += av.x * wvv.z; acc[0][3] += av.x * wvv.w;
    acc[1][0] += av.y * wvv.x; acc[1][1] += av.y * wvv.y; acc[1][2] += av.y * wvv.z; acc[1][3] += av.y * wvv.w;
    acc[2][0] += av.z * wvv.x; acc[2][1] += av.z * wvv.y; acc[2][2] += av.z * wvv.z; acc[2][3] += av.z * wvv.w;
    acc[3][0] += av.w * wvv.x; acc[3][1] += av.w * wvv.y; acc[3][2] += av.w * wvv.z; acc[3][3] += av.w * wvv.w;
  }

  const float4 bv = *(const float4*)(bias + tm * 4);

#pragma unroll
  for (int i = 0; i < 4; ++i) {
    float o0 = acc[i][0] + bv.x, o1 = acc[i][1] + bv.y, o2 = acc[i][2] + bv.z, o3 = acc[i][3] + bv.w;
    float ss = o0 * o0 + o1 * o1 + o2 * o2 + o3 * o3;
#pragma unroll
    for (int off = 32; off > 0; off >>= 1) ss += __shfl_xor(ss, off);
    const float inv = 1.f / fmaxf(sqrtf(ss), 1e-12f);
    o0 *= inv; o1 *= inv; o2 *= inv; o3 *= inv;
    o0 = (o0 >= 0.f) ? o0 : 0.01f * o0;
    o1 = (o1 >= 0.f) ? o1 : 0.01f * o1;
    o2 = (o2 >= 0.f) ? o2 : 0.01f * o2;
    o3 = (o3 >= 0.f) ? o3 : 0.01f * o3;
    ushort4 st;
    st.x = f2bf(o0); st.y = f2bf(o1); st.z = f2bf(o2); st.w = f2bf(o3);
    const int node = node0 + tn * 4 + i;
    if (node < n_nodes) *(ushort4*)(Hout + (size_t)node * M + tm * 4) = st;
  }
}

// ---------------- Layer 3: only the 500 readout nodes ----------------
// One 64-thread block per graph: aggregate neighbors of first-node from h2
// (bf16), then 256->64 GEMM + bias + normalize (no leaky), f32 output.

__global__ __launch_bounds__(64) void layer3_kernel(
    const unsigned short* __restrict__ H2,    // [N, 256] bf16
    const int* __restrict__ indptr, const int* __restrict__ srcs,
    const int* __restrict__ first_node,
    const float* __restrict__ W,              // [256, 64] f32
    const float* __restrict__ bias,           // [64] f32
    float* __restrict__ out)                  // [G, 64] f32
{
  __shared__ float a_s[HID_DIM];
  const int g = blockIdx.x;
  const int lane = threadIdx.x;
  const int node = first_node[g];
  float acc[4] = {0.f, 0.f, 0.f, 0.f};
  const int p1 = indptr[node + 1];
  for (int p = indptr[node]; p < p1; ++p) {
    const int s = srcs[p];
    const ushort4 u = *(const ushort4*)(H2 + (size_t)s * HID_DIM + lane * 4);
    acc[0] += bf2f(u.x); acc[1] += bf2f(u.y); acc[2] += bf2f(u.z); acc[3] += bf2f(u.w);
  }
  *(float4*)&a_s[lane * 4] = make_float4(acc[0], acc[1], acc[2], acc[3]);
  __syncthreads();
  float o = bias[lane];
#pragma unroll 8
  for (int k = 0; k < HID_DIM; ++k) o += a_s[k] * W[k * OUT_DIM + lane];
  float ss = o * o;
#pragma unroll
  for (int off = 32; off > 0; off >>= 1) ss += __shfl_xor(ss, off);
  const float inv = 1.f / fmaxf(sqrtf(ss), 1e-12f);
  out[(size_t)g * OUT_DIM + lane] = o * inv;
}

// ---------------- launch ----------------

extern "C" void kernel_launch(void* const* d_in, const int* in_sizes, int n_in,
                              void* d_out, int out_size, void* d_ws, size_t ws_size,
                              hipStream_t stream) {
  (void)in_sizes; (void)n_in; (void)out_size; (void)ws_size;
  const float* x   = (const float*)d_in[0];
  const int* ei    = (const int*)d_in[1];
  const int* batch = (const int*)d_in[2];
  const float* W1  = (const float*)d_in[3];
  const float* b1  = (const float*)d_in[4];
  const float* W2  = (const float*)d_in[5];
  const float* b2  = (const float*)d_in[6];
  const float* W3  = (const float*)d_in[7];
  const float* b3  = (const float*)d_in[8];
  const int* src = ei;
  const int* dst = ei + E_EDGES;

  char* ws = (char*)d_ws;
  size_t off = 0;
  auto alloc = [&](size_t bytes) {
    void* p = ws + off;
    off = (off + bytes + 255) & ~(size_t)255;
    return p;
  };
  int* deg    = (int*)alloc((size_t)N_NODES * 4);
  int* cursor = (int*)alloc((size_t)N_NODES * 4);
  int* indptr = (int*)alloc((size_t)(N_NODES + 1) * 4);
  int* srcs   = (int*)alloc((size_t)E_EDGES * 4);
  int* first  = (int*)alloc((size_t)G_GRAPHS * 4);
  unsigned short* h1 = (unsigned short*)alloc((size_t)N_NODES * HID_DIM * 2);
  unsigned short* h2 = (unsigned short*)alloc((size_t)N_NODES * HID_DIM * 2);
  // total ~55 MB

  // zero deg + cursor (contiguous region)
  hipMemsetAsync(deg, 0, (size_t)((char*)indptr - (char*)deg), stream);

  count_deg<<<(E_EDGES + 255) / 256, 256, 0, stream>>>(dst, deg);
  scan_indptr<<<1, 256, 0, stream>>>(deg, indptr);
  fill_csr<<<(E_EDGES + 255) / 256, 256, 0, stream>>>(src, dst, indptr, cursor, srcs);
  build_first<<<(N_NODES + 255) / 256, 256, 0, stream>>>(batch, first);

  // Layer 1: x f32 [N,128] -> h1 bf16 [N,256]
  fused_layer<IN_DIM, float><<<(N_NODES + 15) / 16, 256, 0, stream>>>(
      x, indptr, srcs, W1, b1, h1, N_NODES);
  // Layer 2: h1 bf16 [N,256] -> h2 bf16 [N,256]
  fused_layer<HID_DIM, unsigned short><<<(N_NODES + 15) / 16, 256, 0, stream>>>(
      h1, indptr, srcs, W2, b2, h2, N_NODES);
  // Layer 3: only the 500 readout nodes -> f32 out
  layer3_kernel<<<G_GRAPHS, 64, 0, stream>>>(h2, indptr, srcs, first, W3, b3, (float*)d_out);
}

// Round 3
// 520.753 us; speedup vs baseline: 1.1313x; 1.1313x over previous
//
#include <hip/hip_runtime.h>

#define N_NODES 50000
#define E_EDGES 800000
#define IN_DIM  128
#define HID_DIM 256
#define OUT_DIM 64
#define G_GRAPHS 500

__device__ __forceinline__ float bf2f(unsigned short u) {
  union { unsigned int i; float f; } c; c.i = ((unsigned int)u) << 16; return c.f;
}
__device__ __forceinline__ unsigned short f2bf(float f) {
  union { float f; unsigned int i; } c; c.f = f;
  unsigned int x = c.i;
  x += 0x7FFFu + ((x >> 16) & 1u);   // round-to-nearest-even
  return (unsigned short)(x >> 16);
}

// ---------------- CSR build ----------------

__global__ void count_and_first(const int* __restrict__ dst, const int* __restrict__ batch,
                                int* __restrict__ deg, int* __restrict__ first_node) {
  const int e = blockIdx.x * blockDim.x + threadIdx.x;
  if (e < E_EDGES) atomicAdd(&deg[dst[e]], 1);
  if (e < N_NODES) {
    if (e == 0 || batch[e] != batch[e - 1]) first_node[batch[e]] = e;
  }
}

// exclusive scan over N_NODES degrees -> indptr[0..N], one block of 1024
__global__ __launch_bounds__(1024) void scan_indptr(const int* __restrict__ deg,
                                                    int* __restrict__ indptr) {
  __shared__ int sums[1024];
  const int tid = threadIdx.x;
  const int CH = (N_NODES + 1023) / 1024;  // 49
  const int lo = tid * CH;
  const int hi = (lo + CH < N_NODES) ? (lo + CH) : N_NODES;
  int s = 0;
  for (int i = lo; i < hi; ++i) s += deg[i];
  sums[tid] = s;
  __syncthreads();
  for (int off = 1; off < 1024; off <<= 1) {
    int t = (tid >= off) ? sums[tid - off] : 0;
    __syncthreads();
    sums[tid] += t;
    __syncthreads();
  }
  int run = (tid == 0) ? 0 : sums[tid - 1];
  for (int i = lo; i < hi; ++i) { indptr[i] = run; run += deg[i]; }
  if (tid == 1023) indptr[N_NODES] = run;
}

__global__ void fill_csr(const int* __restrict__ src, const int* __restrict__ dst,
                         const int* __restrict__ indptr, int* __restrict__ cursor,
                         int* __restrict__ srcs) {
  const int e = blockIdx.x * blockDim.x + threadIdx.x;
  if (e >= E_EDGES) return;
  const int d = dst[e];
  const int pos = atomicAdd(&cursor[d], 1);
  srcs[indptr[d] + pos] = src[e];
}

// x f32 [N,128] -> bf16
__global__ __launch_bounds__(256) void conv_x(const float* __restrict__ x,
                                              unsigned short* __restrict__ xb) {
  const int i = (blockIdx.x * 256 + threadIdx.x) * 4;
  const float4 v = *(const float4*)(x + i);
  ushort4 u;
  u.x = f2bf(v.x); u.y = f2bf(v.y); u.z = f2bf(v.z); u.w = f2bf(v.w);
  *(ushort4*)(xb + i) = u;
}

// ------- Fused aggregate + GEMM + bias + L2norm + leaky -------
// Block: 256 threads = 4 waves, TN=16 nodes, M=256 outputs. Grid is exact
// (50000/16 = 3125), no bounds checks.
// Phase 1: wave w gathers neighbors for its 4 nodes INTERLEAVED and
//   unrolled x2 -> 8 independent srcs loads + 8 independent row loads in
//   flight (MLP fix for the 130us latency stall seen in round 2). Uniform-
//   branch round-robin tail for the degree imbalance. LDS layout a_s[node][K]
//   -> phase-1 stores are contiguous b64/b128 (conflict-free; round 2's
//   transposed layout was 32-way conflicted, SQ_LDS_BANK_CONFLICT=6e6).
// Phase 2: thread (tm=lane, tn=wave) owns 4x4 micro-tile. k unrolled by 4:
//   per node one broadcast ds_read_b128 covers 4 k's -> same LDS issue cost
//   as round 2, zero conflicts. W read float4/lane coalesced.

template<int K>
__global__ __launch_bounds__(256) void fused_layer(
    const unsigned short* __restrict__ H,     // [N, K] bf16
    const int* __restrict__ indptr, const int* __restrict__ srcs,
    const float* __restrict__ W,              // [K, 256] f32
    const float* __restrict__ bias,           // [256] f32
    unsigned short* __restrict__ Hout)        // [N, 256] bf16
{
  constexpr int M = 256;
  constexpr int TN = 16;
  constexpr int VPT = K / 64;                 // 2 (K=128) or 4 (K=256)
  __shared__ float a_s[TN][K];
  const int tid = threadIdx.x;
  const int lane = tid & 63;
  const int wv = tid >> 6;
  const int nbase = blockIdx.x * TN + wv * 4;

  // ---- Phase 1: interleaved gather ----
  int pb[4], pe[4];
#pragma unroll
  for (int i = 0; i < 4; ++i) { pb[i] = indptr[nbase + i]; pe[i] = indptr[nbase + i + 1]; }
  const int d0 = pe[0] - pb[0], d1 = pe[1] - pb[1], d2 = pe[2] - pb[2], d3 = pe[3] - pb[3];
  const int mind = min(min(d0, d1), min(d2, d3));
  const int maxd = max(max(d0, d1), max(d2, d3));
  const int cnt = mind & ~1;

  float acc[4][VPT];
#pragma unroll
  for (int i = 0; i < 4; ++i)
#pragma unroll
    for (int j = 0; j < VPT; ++j) acc[i][j] = 0.f;

  for (int it = 0; it < cnt; it += 2) {
    int s[8];
#pragma unroll
    for (int i = 0; i < 4; ++i) { s[i] = srcs[pb[i] + it]; s[4 + i] = srcs[pb[i] + it + 1]; }
    if constexpr (VPT == 4) {
      ushort4 r[8];
#pragma unroll
      for (int j = 0; j < 8; ++j) r[j] = *(const ushort4*)(H + (size_t)s[j] * K + lane * 4);
#pragma unroll
      for (int j = 0; j < 8; ++j) {
        const int i = j & 3;
        acc[i][0] += bf2f(r[j].x); acc[i][1] += bf2f(r[j].y);
        acc[i][2] += bf2f(r[j].z); acc[i][3] += bf2f(r[j].w);
      }
    } else {
      ushort2 r[8];
#pragma unroll
      for (int j = 0; j < 8; ++j) r[j] = *(const ushort2*)(H + (size_t)s[j] * K + lane * 2);
#pragma unroll
      for (int j = 0; j < 8; ++j) {
        const int i = j & 3;
        acc[i][0] += bf2f(r[j].x); acc[i][1] += bf2f(r[j].y);
      }
    }
  }
  // tail: round-robin across the 4 nodes, branches are wave-uniform
  for (int it = cnt; it < maxd; ++it) {
#pragma unroll
    for (int i = 0; i < 4; ++i) {
      if (pb[i] + it < pe[i]) {
        const int sv = srcs[pb[i] + it];
        if constexpr (VPT == 4) {
          const ushort4 u = *(const ushort4*)(H + (size_t)sv * K + lane * 4);
          acc[i][0] += bf2f(u.x); acc[i][1] += bf2f(u.y);
          acc[i][2] += bf2f(u.z); acc[i][3] += bf2f(u.w);
        } else {
          const ushort2 u = *(const ushort2*)(H + (size_t)sv * K + lane * 2);
          acc[i][0] += bf2f(u.x); acc[i][1] += bf2f(u.y);
        }
      }
    }
  }
  // store to LDS: contiguous per lane -> conflict-free b64/b128
#pragma unroll
  for (int i = 0; i < 4; ++i) {
    if constexpr (VPT == 4)
      *(float4*)&a_s[wv * 4 + i][lane * 4] = make_float4(acc[i][0], acc[i][1], acc[i][2], acc[i][3]);
    else
      *(float2*)&a_s[wv * 4 + i][lane * 2] = make_float2(acc[i][0], acc[i][1]);
  }
  __syncthreads();

  // ---- Phase 2: GEMM + bias + normalize + leaky ----
  const int tm = lane, tn = wv;
  float o[4][4];
#pragma unroll
  for (int i = 0; i < 4; ++i)
#pragma unroll
    for (int j = 0; j < 4; ++j) o[i][j] = 0.f;

#pragma unroll 2
  for (int k = 0; k < K; k += 4) {
    float4 av[4];
#pragma unroll
    for (int i = 0; i < 4; ++i) av[i] = *(const float4*)&a_s[tn * 4 + i][k];
#pragma unroll
    for (int kk = 0; kk < 4; ++kk) {
      const float4 wr = *(const float4*)(W + (size_t)(k + kk) * M + tm * 4);
#pragma unroll
      for (int i = 0; i < 4; ++i) {
        const float a = ((const float*)&av[i])[kk];
        o[i][0] += a * wr.x; o[i][1] += a * wr.y; o[i][2] += a * wr.z; o[i][3] += a * wr.w;
      }
    }
  }

  const float4 bv = *(const float4*)(bias + tm * 4);
#pragma unroll
  for (int i = 0; i < 4; ++i) {
    float o0 = o[i][0] + bv.x, o1 = o[i][1] + bv.y, o2 = o[i][2] + bv.z, o3 = o[i][3] + bv.w;
    float ss = o0 * o0 + o1 * o1 + o2 * o2 + o3 * o3;
#pragma unroll
    for (int off = 32; off > 0; off >>= 1) ss += __shfl_xor(ss, off);
    const float inv = 1.f / fmaxf(sqrtf(ss), 1e-12f);
    o0 *= inv; o1 *= inv; o2 *= inv; o3 *= inv;
    o0 = (o0 >= 0.f) ? o0 : 0.01f * o0;
    o1 = (o1 >= 0.f) ? o1 : 0.01f * o1;
    o2 = (o2 >= 0.f) ? o2 : 0.01f * o2;
    o3 = (o3 >= 0.f) ? o3 : 0.01f * o3;
    ushort4 st;
    st.x = f2bf(o0); st.y = f2bf(o1); st.z = f2bf(o2); st.w = f2bf(o3);
    const int node = nbase + i;   // == blockIdx*TN + tn*4 + i
    *(ushort4*)(Hout + (size_t)node * M + tm * 4) = st;
  }
}

// ---------------- Layer 3: only the 500 readout nodes ----------------

__global__ __launch_bounds__(64) void layer3_kernel(
    const unsigned short* __restrict__ H2,    // [N, 256] bf16
    const int* __restrict__ indptr, const int* __restrict__ srcs,
    const int* __restrict__ first_node,
    const float* __restrict__ W,              // [256, 64] f32
    const float* __restrict__ bias,           // [64] f32
    float* __restrict__ out)                  // [G, 64] f32
{
  __shared__ float a_s[HID_DIM];
  const int g = blockIdx.x;
  const int lane = threadIdx.x;
  const int node = first_node[g];
  float acc[4] = {0.f, 0.f, 0.f, 0.f};
  const int p1 = indptr[node + 1];
  for (int p = indptr[node]; p < p1; ++p) {
    const int s = srcs[p];
    const ushort4 u = *(const ushort4*)(H2 + (size_t)s * HID_DIM + lane * 4);
    acc[0] += bf2f(u.x); acc[1] += bf2f(u.y); acc[2] += bf2f(u.z); acc[3] += bf2f(u.w);
  }
  *(float4*)&a_s[lane * 4] = make_float4(acc[0], acc[1], acc[2], acc[3]);
  __syncthreads();
  float o = bias[lane];
#pragma unroll 8
  for (int k = 0; k < HID_DIM; ++k) o += a_s[k] * W[k * OUT_DIM + lane];
  float ss = o * o;
#pragma unroll
  for (int off = 32; off > 0; off >>= 1) ss += __shfl_xor(ss, off);
  const float inv = 1.f / fmaxf(sqrtf(ss), 1e-12f);
  out[(size_t)g * OUT_DIM + lane] = o * inv;
}

// ---------------- launch ----------------

extern "C" void kernel_launch(void* const* d_in, const int* in_sizes, int n_in,
                              void* d_out, int out_size, void* d_ws, size_t ws_size,
                              hipStream_t stream) {
  (void)in_sizes; (void)n_in; (void)out_size; (void)ws_size;
  const float* x   = (const float*)d_in[0];
  const int* ei    = (const int*)d_in[1];
  const int* batch = (const int*)d_in[2];
  const float* W1  = (const float*)d_in[3];
  const float* b1  = (const float*)d_in[4];
  const float* W2  = (const float*)d_in[5];
  const float* b2  = (const float*)d_in[6];
  const float* W3  = (const float*)d_in[7];
  const float* b3  = (const float*)d_in[8];
  const int* src = ei;
  const int* dst = ei + E_EDGES;

  char* ws = (char*)d_ws;
  size_t off = 0;
  auto alloc = [&](size_t bytes) {
    void* p = ws + off;
    off = (off + bytes + 255) & ~(size_t)255;
    return p;
  };
  int* deg    = (int*)alloc((size_t)N_NODES * 4);
  int* cursor = (int*)alloc((size_t)N_NODES * 4);
  int* indptr = (int*)alloc((size_t)(N_NODES + 1) * 4);
  int* srcs   = (int*)alloc((size_t)E_EDGES * 4);
  int* first  = (int*)alloc((size_t)G_GRAPHS * 4);
  // region A: h2 [N,256] bf16; its first half doubles as xb [N,128] bf16
  // (xb is dead after layer 1; h2 is born in layer 2 -> no overlap in time)
  unsigned short* h2 = (unsigned short*)alloc((size_t)N_NODES * HID_DIM * 2);
  unsigned short* xb = h2;
  unsigned short* h1 = (unsigned short*)alloc((size_t)N_NODES * HID_DIM * 2);
  // total ~55 MB

  // zero deg + cursor (contiguous region)
  hipMemsetAsync(deg, 0, (size_t)((char*)indptr - (char*)deg), stream);

  count_and_first<<<(E_EDGES + 255) / 256, 256, 0, stream>>>(dst, batch, deg, first);
  scan_indptr<<<1, 1024, 0, stream>>>(deg, indptr);
  fill_csr<<<(E_EDGES + 255) / 256, 256, 0, stream>>>(src, dst, indptr, cursor, srcs);
  conv_x<<<(N_NODES * IN_DIM / 4) / 256, 256, 0, stream>>>(x, xb);

  // Layer 1: xb bf16 [N,128] -> h1 bf16 [N,256]
  fused_layer<IN_DIM><<<N_NODES / 16, 256, 0, stream>>>(xb, indptr, srcs, W1, b1, h1);
  // Layer 2: h1 bf16 [N,256] -> h2 bf16 [N,256]
  fused_layer<HID_DIM><<<N_NODES / 16, 256, 0, stream>>>(h1, indptr, srcs, W2, b2, h2);
  // Layer 3: only the 500 readout nodes -> f32 out
  layer3_kernel<<<G_GRAPHS, 64, 0, stream>>>(h2, indptr, srcs, first, W3, b3, (float*)d_out);
}

// Round 4
// 456.738 us; speedup vs baseline: 1.2899x; 1.1402x over previous
//
#include <hip/hip_runtime.h>

#define N_NODES 50000
#define E_EDGES 800000
#define IN_DIM  128
#define HID_DIM 256
#define OUT_DIM 64
#define G_GRAPHS 500

typedef __attribute__((ext_vector_type(8))) short short8;    // 8 bf16 = 4 VGPRs (MFMA A/B frag)
typedef __attribute__((ext_vector_type(4))) float float4v;   // MFMA C/D frag

__device__ __forceinline__ float bf2f(unsigned short u) {
  union { unsigned int i; float f; } c; c.i = ((unsigned int)u) << 16; return c.f;
}
__device__ __forceinline__ unsigned short f2bf(float f) {
  union { float f; unsigned int i; } c; c.f = f;
  unsigned int x = c.i;
  x += 0x7FFFu + ((x >> 16) & 1u);   // round-to-nearest-even
  return (unsigned short)(x >> 16);
}
__device__ __forceinline__ unsigned int fbits(float f) {
  union { float f; unsigned int i; } c; c.f = f; return c.i;
}
__device__ __forceinline__ float bits2f(unsigned int u) {
  union { unsigned int i; float f; } c; c.i = u; return c.f;
}

// ---------------- CSR build ----------------

__global__ void count_and_first(const int* __restrict__ dst, const int* __restrict__ batch,
                                int* __restrict__ deg, int* __restrict__ first_node) {
  const int e = blockIdx.x * blockDim.x + threadIdx.x;
  if (e < E_EDGES) atomicAdd(&deg[dst[e]], 1);
  if (e < N_NODES) {
    if (e == 0 || batch[e] != batch[e - 1]) first_node[batch[e]] = e;
  }
}

__global__ __launch_bounds__(1024) void scan_indptr(const int* __restrict__ deg,
                                                    int* __restrict__ indptr) {
  __shared__ int sums[1024];
  const int tid = threadIdx.x;
  const int CH = (N_NODES + 1023) / 1024;  // 49
  const int lo = tid * CH;
  const int hi = (lo + CH < N_NODES) ? (lo + CH) : N_NODES;
  int s = 0;
  for (int i = lo; i < hi; ++i) s += deg[i];
  sums[tid] = s;
  __syncthreads();
  for (int off = 1; off < 1024; off <<= 1) {
    int t = (tid >= off) ? sums[tid - off] : 0;
    __syncthreads();
    sums[tid] += t;
    __syncthreads();
  }
  int run = (tid == 0) ? 0 : sums[tid - 1];
  for (int i = lo; i < hi; ++i) { indptr[i] = run; run += deg[i]; }
  if (tid == 1023) indptr[N_NODES] = run;
}

__global__ void fill_csr(const int* __restrict__ src, const int* __restrict__ dst,
                         const int* __restrict__ indptr, int* __restrict__ cursor,
                         int* __restrict__ srcs) {
  const int e = blockIdx.x * blockDim.x + threadIdx.x;
  if (e >= E_EDGES) return;
  const int d = dst[e];
  const int pos = atomicAdd(&cursor[d], 1);
  srcs[indptr[d] + pos] = src[e];
}

// x f32 [N,128] -> bf16 (halves layer-1 gather traffic)
__global__ __launch_bounds__(256) void conv_x(const float* __restrict__ x,
                                              unsigned short* __restrict__ xb) {
  const int i = (blockIdx.x * 256 + threadIdx.x) * 4;
  const float4 v = *(const float4*)(x + i);
  ushort4 u;
  u.x = f2bf(v.x); u.y = f2bf(v.y); u.z = f2bf(v.z); u.w = f2bf(v.w);
  *(ushort4*)(xb + i) = u;
}

// W1 [128,256] -> W1t [256 n][128 k] bf16 ; W2 [256,256] -> W2t [256 n][256 k] bf16
// (B^T layout: MFMA B-frag = 8 contiguous k per lane)
__global__ __launch_bounds__(64) void prep_w(const float* __restrict__ W1,
                                             const float* __restrict__ W2,
                                             unsigned short* __restrict__ W1t,
                                             unsigned short* __restrict__ W2t) {
  const int b = blockIdx.x, t = threadIdx.x;
  if (b < 256) {
    const int n = b;
    ushort2 o;
    o.x = f2bf(W1[(2 * t) * 256 + n]);
    o.y = f2bf(W1[(2 * t + 1) * 256 + n]);
    *(ushort2*)&W1t[n * 128 + 2 * t] = o;
  } else {
    const int n = b - 256;
    ushort4 o;
    o.x = f2bf(W2[(4 * t + 0) * 256 + n]);
    o.y = f2bf(W2[(4 * t + 1) * 256 + n]);
    o.z = f2bf(W2[(4 * t + 2) * 256 + n]);
    o.w = f2bf(W2[(4 * t + 3) * 256 + n]);
    *(ushort4*)&W2t[n * 256 + 4 * t] = o;
  }
}

// ------- Fused aggregate + MFMA GEMM + bias + L2norm + leaky -------
// Block: 256 thr = 4 waves, 16 nodes, 256 outs. Grid exact (3125).
// Phase 1: round-3 interleaved MLP gather (8 rows in flight), fp32 acc.
//   Then split acc into bf16 hi + residual lo, store both to LDS
//   a_{hi,lo}[16][K+8] (row stride 528B/272B: 16B-aligned; write banks land
//   exactly on the words/bank floor -> no excess conflict).
// Phase 2: wave w owns n in [w*64, w*64+64): 4 n-tiles x K/32 k-steps of
//   mfma_f32_16x16x32_bf16, 2 MFMAs (hi,lo) per B-frag into one fp32 acc.
//   A-frag: lane reads a_*[lane&15][ks*32+(lane>>4)*8] = ds_read_b128.
//   B-frag: Wt[n=ntile*16+(lane&15)][ks*32+(lane>>4)*8] = global dwordx4 (L2-hot).
//   C/D layout (m89/m91): n = lane&15 (+16*ntile), node = (lane>>4)*4+reg.
// Epilogue: bias, per-node sumsq: intra-wave shfl_xor over the 16-lane
//   column group, cross-wave via ssq[4][16] in LDS; rsqrt, leaky, RNE bf16.

template<int K>
__global__ __launch_bounds__(256) void fused_layer(
    const unsigned short* __restrict__ H,     // [N, K] bf16
    const int* __restrict__ indptr, const int* __restrict__ srcs,
    const unsigned short* __restrict__ Wt,    // [256 n][K k] bf16
    const float* __restrict__ bias,           // [256] f32
    unsigned short* __restrict__ Hout)        // [N, 256] bf16
{
  constexpr int M = 256;
  constexpr int TN = 16;
  constexpr int VPT = K / 64;                 // 2 (K=128) or 4 (K=256)
  constexpr int LDK = K + 8;                  // +16B pad per row
  __shared__ unsigned short a_hi[TN][LDK];
  __shared__ unsigned short a_lo[TN][LDK];
  __shared__ float ssq[4][16];
  const int tid = threadIdx.x;
  const int lane = tid & 63;
  const int wv = tid >> 6;
  const int nbase = blockIdx.x * TN + wv * 4;

  // ---- Phase 1: interleaved gather (fp32 acc) ----
  int pb[4], pe[4];
#pragma unroll
  for (int i = 0; i < 4; ++i) { pb[i] = indptr[nbase + i]; pe[i] = indptr[nbase + i + 1]; }
  const int d0 = pe[0] - pb[0], d1 = pe[1] - pb[1], d2 = pe[2] - pb[2], d3 = pe[3] - pb[3];
  const int mind = min(min(d0, d1), min(d2, d3));
  const int maxd = max(max(d0, d1), max(d2, d3));
  const int cnt = mind & ~1;

  float acc[4][VPT];
#pragma unroll
  for (int i = 0; i < 4; ++i)
#pragma unroll
    for (int j = 0; j < VPT; ++j) acc[i][j] = 0.f;

  for (int it = 0; it < cnt; it += 2) {
    int s[8];
#pragma unroll
    for (int i = 0; i < 4; ++i) { s[i] = srcs[pb[i] + it]; s[4 + i] = srcs[pb[i] + it + 1]; }
    if constexpr (VPT == 4) {
      ushort4 r[8];
#pragma unroll
      for (int j = 0; j < 8; ++j) r[j] = *(const ushort4*)(H + (size_t)s[j] * K + lane * 4);
#pragma unroll
      for (int j = 0; j < 8; ++j) {
        const int i = j & 3;
        acc[i][0] += bf2f(r[j].x); acc[i][1] += bf2f(r[j].y);
        acc[i][2] += bf2f(r[j].z); acc[i][3] += bf2f(r[j].w);
      }
    } else {
      ushort2 r[8];
#pragma unroll
      for (int j = 0; j < 8; ++j) r[j] = *(const ushort2*)(H + (size_t)s[j] * K + lane * 2);
#pragma unroll
      for (int j = 0; j < 8; ++j) {
        const int i = j & 3;
        acc[i][0] += bf2f(r[j].x); acc[i][1] += bf2f(r[j].y);
      }
    }
  }
  for (int it = cnt; it < maxd; ++it) {
#pragma unroll
    for (int i = 0; i < 4; ++i) {
      if (pb[i] + it < pe[i]) {
        const int sv = srcs[pb[i] + it];
        if constexpr (VPT == 4) {
          const ushort4 u = *(const ushort4*)(H + (size_t)sv * K + lane * 4);
          acc[i][0] += bf2f(u.x); acc[i][1] += bf2f(u.y);
          acc[i][2] += bf2f(u.z); acc[i][3] += bf2f(u.w);
        } else {
          const ushort2 u = *(const ushort2*)(H + (size_t)sv * K + lane * 2);
          acc[i][0] += bf2f(u.x); acc[i][1] += bf2f(u.y);
        }
      }
    }
  }

  // split fp32 acc -> bf16 hi + bf16(residual) lo; store to LDS
#pragma unroll
  for (int i = 0; i < 4; ++i) {
    const int nn = wv * 4 + i;
    unsigned short h[VPT], l[VPT];
#pragma unroll
    for (int j = 0; j < VPT; ++j) {
      const unsigned int u = fbits(acc[i][j]);
      h[j] = (unsigned short)(u >> 16);                       // truncated hi
      const float res = acc[i][j] - bits2f(u & 0xFFFF0000u);  // exact residual
      l[j] = (unsigned short)(fbits(res) >> 16);
    }
    if constexpr (VPT == 4) {
      *(ushort4*)&a_hi[nn][lane * 4] = make_ushort4(h[0], h[1], h[2], h[3]);
      *(ushort4*)&a_lo[nn][lane * 4] = make_ushort4(l[0], l[1], l[2], l[3]);
    } else {
      *(ushort2*)&a_hi[nn][lane * 2] = make_ushort2(h[0], h[1]);
      *(ushort2*)&a_lo[nn][lane * 2] = make_ushort2(l[0], l[1]);
    }
  }
  __syncthreads();

  // ---- Phase 2: MFMA GEMM ----
  const int g = lane >> 4;       // k-group / node-row group
  const int lc = lane & 15;      // n within tile / A row (m)
  float4v dacc[4];
#pragma unroll
  for (int nt = 0; nt < 4; ++nt) dacc[nt] = (float4v){0.f, 0.f, 0.f, 0.f};

#pragma unroll
  for (int ks = 0; ks < K / 32; ++ks) {
    const short8 ah = *(const short8*)&a_hi[lc][ks * 32 + g * 8];
    const short8 al = *(const short8*)&a_lo[lc][ks * 32 + g * 8];
#pragma unroll
    for (int nt = 0; nt < 4; ++nt) {
      const int n = wv * 64 + nt * 16 + lc;
      const short8 bw = *(const short8*)(Wt + (size_t)n * K + ks * 32 + g * 8);
      dacc[nt] = __builtin_amdgcn_mfma_f32_16x16x32_bf16(ah, bw, dacc[nt], 0, 0, 0);
      dacc[nt] = __builtin_amdgcn_mfma_f32_16x16x32_bf16(al, bw, dacc[nt], 0, 0, 0);
    }
  }

  // ---- Epilogue: bias + cross-wave L2 norm + leaky + store ----
  float4v o[4];
  float sq[4] = {0.f, 0.f, 0.f, 0.f};        // per reg r (node = g*4+r)
#pragma unroll
  for (int nt = 0; nt < 4; ++nt) {
    const float bn = bias[wv * 64 + nt * 16 + lc];
    o[nt] = dacc[nt] + bn;
#pragma unroll
    for (int r = 0; r < 4; ++r) sq[r] += o[nt][r] * o[nt][r];
  }
#pragma unroll
  for (int off = 1; off < 16; off <<= 1) {
#pragma unroll
    for (int r = 0; r < 4; ++r) sq[r] += __shfl_xor(sq[r], off);
  }
  if (lc == 0) *(float4*)&ssq[wv][g * 4] = make_float4(sq[0], sq[1], sq[2], sq[3]);
  __syncthreads();
  const float4 t0 = *(const float4*)&ssq[0][g * 4];
  const float4 t1 = *(const float4*)&ssq[1][g * 4];
  const float4 t2 = *(const float4*)&ssq[2][g * 4];
  const float4 t3 = *(const float4*)&ssq[3][g * 4];
  float inv[4];
  inv[0] = 1.f / fmaxf(sqrtf(t0.x + t1.x + t2.x + t3.x), 1e-12f);
  inv[1] = 1.f / fmaxf(sqrtf(t0.y + t1.y + t2.y + t3.y), 1e-12f);
  inv[2] = 1.f / fmaxf(sqrtf(t0.z + t1.z + t2.z + t3.z), 1e-12f);
  inv[3] = 1.f / fmaxf(sqrtf(t0.w + t1.w + t2.w + t3.w), 1e-12f);

  const int node0 = blockIdx.x * TN + g * 4;
#pragma unroll
  for (int nt = 0; nt < 4; ++nt) {
    const int n = wv * 64 + nt * 16 + lc;
#pragma unroll
    for (int r = 0; r < 4; ++r) {
      float v = o[nt][r] * inv[r];
      v = (v >= 0.f) ? v : 0.01f * v;
      Hout[(size_t)(node0 + r) * M + n] = f2bf(v);
    }
  }
}

// ---------------- Layer 3: only the 500 readout nodes ----------------

__global__ __launch_bounds__(64) void layer3_kernel(
    const unsigned short* __restrict__ H2,    // [N, 256] bf16
    const int* __restrict__ indptr, const int* __restrict__ srcs,
    const int* __restrict__ first_node,
    const float* __restrict__ W,              // [256, 64] f32
    const float* __restrict__ bias,           // [64] f32
    float* __restrict__ out)                  // [G, 64] f32
{
  __shared__ float a_s[HID_DIM];
  const int g = blockIdx.x;
  const int lane = threadIdx.x;
  const int node = first_node[g];
  float acc[4] = {0.f, 0.f, 0.f, 0.f};
  const int p1 = indptr[node + 1];
  for (int p = indptr[node]; p < p1; ++p) {
    const int s = srcs[p];
    const ushort4 u = *(const ushort4*)(H2 + (size_t)s * HID_DIM + lane * 4);
    acc[0] += bf2f(u.x); acc[1] += bf2f(u.y); acc[2] += bf2f(u.z); acc[3] += bf2f(u.w);
  }
  *(float4*)&a_s[lane * 4] = make_float4(acc[0], acc[1], acc[2], acc[3]);
  __syncthreads();
  float o = bias[lane];
#pragma unroll 8
  for (int k = 0; k < HID_DIM; ++k) o += a_s[k] * W[k * OUT_DIM + lane];
  float ss = o * o;
#pragma unroll
  for (int off = 32; off > 0; off >>= 1) ss += __shfl_xor(ss, off);
  const float inv = 1.f / fmaxf(sqrtf(ss), 1e-12f);
  out[(size_t)g * OUT_DIM + lane] = o * inv;
}

// ---------------- launch ----------------

extern "C" void kernel_launch(void* const* d_in, const int* in_sizes, int n_in,
                              void* d_out, int out_size, void* d_ws, size_t ws_size,
                              hipStream_t stream) {
  (void)in_sizes; (void)n_in; (void)out_size; (void)ws_size;
  const float* x   = (const float*)d_in[0];
  const int* ei    = (const int*)d_in[1];
  const int* batch = (const int*)d_in[2];
  const float* W1  = (const float*)d_in[3];
  const float* b1  = (const float*)d_in[4];
  const float* W2  = (const float*)d_in[5];
  const float* b2  = (const float*)d_in[6];
  const float* W3  = (const float*)d_in[7];
  const float* b3  = (const float*)d_in[8];
  const int* src = ei;
  const int* dst = ei + E_EDGES;

  char* ws = (char*)d_ws;
  size_t off = 0;
  auto alloc = [&](size_t bytes) {
    void* p = ws + off;
    off = (off + bytes + 255) & ~(size_t)255;
    return p;
  };
  int* deg    = (int*)alloc((size_t)N_NODES * 4);
  int* cursor = (int*)alloc((size_t)N_NODES * 4);
  int* indptr = (int*)alloc((size_t)(N_NODES + 1) * 4);
  int* srcs   = (int*)alloc((size_t)E_EDGES * 4);
  int* first  = (int*)alloc((size_t)G_GRAPHS * 4);
  unsigned short* W1t = (unsigned short*)alloc((size_t)256 * 128 * 2);
  unsigned short* W2t = (unsigned short*)alloc((size_t)256 * 256 * 2);
  // region: h2 [N,256] bf16; first half doubles as xb [N,128] bf16
  unsigned short* h2 = (unsigned short*)alloc((size_t)N_NODES * HID_DIM * 2);
  unsigned short* xb = h2;
  unsigned short* h1 = (unsigned short*)alloc((size_t)N_NODES * HID_DIM * 2);

  hipMemsetAsync(deg, 0, (size_t)((char*)indptr - (char*)deg), stream);

  count_and_first<<<(E_EDGES + 255) / 256, 256, 0, stream>>>(dst, batch, deg, first);
  scan_indptr<<<1, 1024, 0, stream>>>(deg, indptr);
  fill_csr<<<(E_EDGES + 255) / 256, 256, 0, stream>>>(src, dst, indptr, cursor, srcs);
  conv_x<<<(N_NODES * IN_DIM / 4) / 256, 256, 0, stream>>>(x, xb);
  prep_w<<<512, 64, 0, stream>>>(W1, W2, W1t, W2t);

  // Layer 1: xb bf16 [N,128] -> h1 bf16 [N,256]
  fused_layer<IN_DIM><<<N_NODES / 16, 256, 0, stream>>>(xb, indptr, srcs, W1t, b1, h1);
  // Layer 2: h1 bf16 [N,256] -> h2 bf16 [N,256]
  fused_layer<HID_DIM><<<N_NODES / 16, 256, 0, stream>>>(h1, indptr, srcs, W2t, b2, h2);
  // Layer 3: only the 500 readout nodes -> f32 out
  layer3_kernel<<<G_GRAPHS, 64, 0, stream>>>(h2, indptr, srcs, first, W3, b3, (float*)d_out);
}

// Round 5
// 407.200 us; speedup vs baseline: 1.4468x; 1.1217x over previous
//
#include <hip/hip_runtime.h>

#define N_NODES 50000
#define E_EDGES 800000
#define IN_DIM  128
#define HID_DIM 256
#define OUT_DIM 64
#define G_GRAPHS 500

typedef __attribute__((ext_vector_type(8))) short short8;    // 8 bf16 = 4 VGPRs (MFMA A/B frag)
typedef __attribute__((ext_vector_type(4))) float float4v;   // MFMA C/D frag

__device__ __forceinline__ float bf2f(unsigned short u) {
  union { unsigned int i; float f; } c; c.i = ((unsigned int)u) << 16; return c.f;
}
__device__ __forceinline__ unsigned short f2bf(float f) {
  union { float f; unsigned int i; } c; c.f = f;
  unsigned int x = c.i;
  x += 0x7FFFu + ((x >> 16) & 1u);   // round-to-nearest-even
  return (unsigned short)(x >> 16);
}
__device__ __forceinline__ unsigned int fbits(float f) {
  union { float f; unsigned int i; } c; c.f = f; return c.i;
}
__device__ __forceinline__ float bits2f(unsigned int u) {
  union { unsigned int i; float f; } c; c.i = u; return c.f;
}

// ---------------- CSR build ----------------

__global__ void count_and_first(const int* __restrict__ dst, const int* __restrict__ batch,
                                int* __restrict__ deg, int* __restrict__ first_node) {
  const int e = blockIdx.x * blockDim.x + threadIdx.x;
  if (e < E_EDGES) atomicAdd(&deg[dst[e]], 1);
  if (e < N_NODES) {
    if (e == 0 || batch[e] != batch[e - 1]) first_node[batch[e]] = e;
  }
}

__global__ __launch_bounds__(1024) void scan_indptr(const int* __restrict__ deg,
                                                    int* __restrict__ indptr) {
  __shared__ int sums[1024];
  const int tid = threadIdx.x;
  const int CH = (N_NODES + 1023) / 1024;  // 49
  const int lo = tid * CH;
  const int hi = (lo + CH < N_NODES) ? (lo + CH) : N_NODES;
  int s = 0;
  for (int i = lo; i < hi; ++i) s += deg[i];
  sums[tid] = s;
  __syncthreads();
  for (int off = 1; off < 1024; off <<= 1) {
    int t = (tid >= off) ? sums[tid - off] : 0;
    __syncthreads();
    sums[tid] += t;
    __syncthreads();
  }
  int run = (tid == 0) ? 0 : sums[tid - 1];
  for (int i = lo; i < hi; ++i) { indptr[i] = run; run += deg[i]; }
  if (tid == 1023) indptr[N_NODES] = run;
}

__global__ void fill_csr(const int* __restrict__ src, const int* __restrict__ dst,
                         const int* __restrict__ indptr, int* __restrict__ cursor,
                         int* __restrict__ srcs) {
  const int e = blockIdx.x * blockDim.x + threadIdx.x;
  if (e >= E_EDGES) return;
  const int d = dst[e];
  const int pos = atomicAdd(&cursor[d], 1);
  srcs[indptr[d] + pos] = src[e];
}

// x f32 [N,128] -> bf16 (halves layer-1 gather traffic)
__global__ __launch_bounds__(256) void conv_x(const float* __restrict__ x,
                                              unsigned short* __restrict__ xb) {
  const int i = (blockIdx.x * 256 + threadIdx.x) * 4;
  const float4 v = *(const float4*)(x + i);
  ushort4 u;
  u.x = f2bf(v.x); u.y = f2bf(v.y); u.z = f2bf(v.z); u.w = f2bf(v.w);
  *(ushort4*)(xb + i) = u;
}

// W1 [128,256] -> W1t [256 n][128 k] bf16 ; W2 [256,256] -> W2t [256 n][256 k] bf16
__global__ __launch_bounds__(64) void prep_w(const float* __restrict__ W1,
                                             const float* __restrict__ W2,
                                             unsigned short* __restrict__ W1t,
                                             unsigned short* __restrict__ W2t) {
  const int b = blockIdx.x, t = threadIdx.x;
  if (b < 256) {
    const int n = b;
    ushort2 o;
    o.x = f2bf(W1[(2 * t) * 256 + n]);
    o.y = f2bf(W1[(2 * t + 1) * 256 + n]);
    *(ushort2*)&W1t[n * 128 + 2 * t] = o;
  } else {
    const int n = b - 256;
    ushort4 o;
    o.x = f2bf(W2[(4 * t + 0) * 256 + n]);
    o.y = f2bf(W2[(4 * t + 1) * 256 + n]);
    o.z = f2bf(W2[(4 * t + 2) * 256 + n]);
    o.w = f2bf(W2[(4 * t + 3) * 256 + n]);
    *(ushort4*)&W2t[n * 256 + 4 * t] = o;
  }
}

// ------- Fused aggregate + MFMA GEMM + bias + L2norm + leaky -------
// Phase 1 (round 5): scalarized windowed gather. nbase is forced wave-uniform
// via readfirstlane -> all loop state (p, pe, window base) is SGPR; edge ids
// come from a 64-wide register window (1 coalesced srcs load per 64 edges,
// CSR ranges of the wave's 4 nodes are contiguous) via v_readlane -> row
// loads are single-level dependent, scalar-addressed, issued 4 deep.
// Phase 2 + epilogue: unchanged from round 4 (hi/lo split MFMA, exact).

template<int K>
__global__ __launch_bounds__(256) void fused_layer(
    const unsigned short* __restrict__ H,     // [N, K] bf16
    const int* __restrict__ indptr, const int* __restrict__ srcs,
    const unsigned short* __restrict__ Wt,    // [256 n][K k] bf16
    const float* __restrict__ bias,           // [256] f32
    unsigned short* __restrict__ Hout)        // [N, 256] bf16
{
  constexpr int M = 256;
  constexpr int TN = 16;
  constexpr int VPT = K / 64;                 // 2 (K=128) or 4 (K=256)
  constexpr int LDK = K + 8;                  // +16B pad per row
  __shared__ unsigned short a_hi[TN][LDK];
  __shared__ unsigned short a_lo[TN][LDK];
  __shared__ float ssq[4][16];
  const int tid = threadIdx.x;
  const int lane = tid & 63;
  const int wv = tid >> 6;

  // ---- Phase 1: scalarized windowed gather ----
  const int nb = __builtin_amdgcn_readfirstlane(blockIdx.x * TN + wv * 4);
  int pp[5];
#pragma unroll
  for (int i = 0; i < 5; ++i) pp[i] = indptr[nb + i];   // uniform -> s_load

  float acc[4][VPT];
#pragma unroll
  for (int i = 0; i < 4; ++i)
#pragma unroll
    for (int j = 0; j < VPT; ++j) acc[i][j] = 0.f;

  int cbase = pp[0];
  int idx = srcs[cbase + lane];               // 64-edge index window (srcs padded +64)

#pragma unroll
  for (int i = 0; i < 4; ++i) {
    int p = pp[i];
    const int pe = pp[i + 1];
    while (p + 4 <= pe) {
      if (p + 4 > cbase + 64) { cbase = p; idx = srcs[cbase + lane]; }
      const int o = p - cbase;
      const int s0 = __builtin_amdgcn_readlane(idx, o);
      const int s1 = __builtin_amdgcn_readlane(idx, o + 1);
      const int s2 = __builtin_amdgcn_readlane(idx, o + 2);
      const int s3 = __builtin_amdgcn_readlane(idx, o + 3);
      if constexpr (VPT == 4) {
        const ushort4 r0 = *(const ushort4*)(H + (size_t)s0 * K + lane * 4);
        const ushort4 r1 = *(const ushort4*)(H + (size_t)s1 * K + lane * 4);
        const ushort4 r2 = *(const ushort4*)(H + (size_t)s2 * K + lane * 4);
        const ushort4 r3 = *(const ushort4*)(H + (size_t)s3 * K + lane * 4);
        acc[i][0] += bf2f(r0.x); acc[i][1] += bf2f(r0.y); acc[i][2] += bf2f(r0.z); acc[i][3] += bf2f(r0.w);
        acc[i][0] += bf2f(r1.x); acc[i][1] += bf2f(r1.y); acc[i][2] += bf2f(r1.z); acc[i][3] += bf2f(r1.w);
        acc[i][0] += bf2f(r2.x); acc[i][1] += bf2f(r2.y); acc[i][2] += bf2f(r2.z); acc[i][3] += bf2f(r2.w);
        acc[i][0] += bf2f(r3.x); acc[i][1] += bf2f(r3.y); acc[i][2] += bf2f(r3.z); acc[i][3] += bf2f(r3.w);
      } else {
        const ushort2 r0 = *(const ushort2*)(H + (size_t)s0 * K + lane * 2);
        const ushort2 r1 = *(const ushort2*)(H + (size_t)s1 * K + lane * 2);
        const ushort2 r2 = *(const ushort2*)(H + (size_t)s2 * K + lane * 2);
        const ushort2 r3 = *(const ushort2*)(H + (size_t)s3 * K + lane * 2);
        acc[i][0] += bf2f(r0.x); acc[i][1] += bf2f(r0.y);
        acc[i][0] += bf2f(r1.x); acc[i][1] += bf2f(r1.y);
        acc[i][0] += bf2f(r2.x); acc[i][1] += bf2f(r2.y);
        acc[i][0] += bf2f(r3.x); acc[i][1] += bf2f(r3.y);
      }
      p += 4;
    }
    while (p < pe) {
      if (p >= cbase + 64) { cbase = p; idx = srcs[cbase + lane]; }
      const int s0 = __builtin_amdgcn_readlane(idx, p - cbase);
      if constexpr (VPT == 4) {
        const ushort4 u = *(const ushort4*)(H + (size_t)s0 * K + lane * 4);
        acc[i][0] += bf2f(u.x); acc[i][1] += bf2f(u.y);
        acc[i][2] += bf2f(u.z); acc[i][3] += bf2f(u.w);
      } else {
        const ushort2 u = *(const ushort2*)(H + (size_t)s0 * K + lane * 2);
        acc[i][0] += bf2f(u.x); acc[i][1] += bf2f(u.y);
      }
      ++p;
    }
  }

  // split fp32 acc -> bf16 hi + bf16(residual) lo; store to LDS
#pragma unroll
  for (int i = 0; i < 4; ++i) {
    const int nn = wv * 4 + i;
    unsigned short h[VPT], l[VPT];
#pragma unroll
    for (int j = 0; j < VPT; ++j) {
      const unsigned int u = fbits(acc[i][j]);
      h[j] = (unsigned short)(u >> 16);                       // truncated hi
      const float res = acc[i][j] - bits2f(u & 0xFFFF0000u);  // exact residual
      l[j] = (unsigned short)(fbits(res) >> 16);
    }
    if constexpr (VPT == 4) {
      *(ushort4*)&a_hi[nn][lane * 4] = make_ushort4(h[0], h[1], h[2], h[3]);
      *(ushort4*)&a_lo[nn][lane * 4] = make_ushort4(l[0], l[1], l[2], l[3]);
    } else {
      *(ushort2*)&a_hi[nn][lane * 2] = make_ushort2(h[0], h[1]);
      *(ushort2*)&a_lo[nn][lane * 2] = make_ushort2(l[0], l[1]);
    }
  }
  __syncthreads();

  // ---- Phase 2: MFMA GEMM ----
  const int g = lane >> 4;       // k-group / node-row group
  const int lc = lane & 15;      // n within tile / A row (m)
  float4v dacc[4];
#pragma unroll
  for (int nt = 0; nt < 4; ++nt) dacc[nt] = (float4v){0.f, 0.f, 0.f, 0.f};

#pragma unroll
  for (int ks = 0; ks < K / 32; ++ks) {
    const short8 ah = *(const short8*)&a_hi[lc][ks * 32 + g * 8];
    const short8 al = *(const short8*)&a_lo[lc][ks * 32 + g * 8];
#pragma unroll
    for (int nt = 0; nt < 4; ++nt) {
      const int n = wv * 64 + nt * 16 + lc;
      const short8 bw = *(const short8*)(Wt + (size_t)n * K + ks * 32 + g * 8);
      dacc[nt] = __builtin_amdgcn_mfma_f32_16x16x32_bf16(ah, bw, dacc[nt], 0, 0, 0);
      dacc[nt] = __builtin_amdgcn_mfma_f32_16x16x32_bf16(al, bw, dacc[nt], 0, 0, 0);
    }
  }

  // ---- Epilogue: bias + cross-wave L2 norm + leaky + store ----
  float4v o[4];
  float sq[4] = {0.f, 0.f, 0.f, 0.f};        // per reg r (node = g*4+r)
#pragma unroll
  for (int nt = 0; nt < 4; ++nt) {
    const float bn = bias[wv * 64 + nt * 16 + lc];
    o[nt] = dacc[nt] + bn;
#pragma unroll
    for (int r = 0; r < 4; ++r) sq[r] += o[nt][r] * o[nt][r];
  }
#pragma unroll
  for (int off = 1; off < 16; off <<= 1) {
#pragma unroll
    for (int r = 0; r < 4; ++r) sq[r] += __shfl_xor(sq[r], off);
  }
  if (lc == 0) *(float4*)&ssq[wv][g * 4] = make_float4(sq[0], sq[1], sq[2], sq[3]);
  __syncthreads();
  const float4 t0 = *(const float4*)&ssq[0][g * 4];
  const float4 t1 = *(const float4*)&ssq[1][g * 4];
  const float4 t2 = *(const float4*)&ssq[2][g * 4];
  const float4 t3 = *(const float4*)&ssq[3][g * 4];
  float inv[4];
  inv[0] = 1.f / fmaxf(sqrtf(t0.x + t1.x + t2.x + t3.x), 1e-12f);
  inv[1] = 1.f / fmaxf(sqrtf(t0.y + t1.y + t2.y + t3.y), 1e-12f);
  inv[2] = 1.f / fmaxf(sqrtf(t0.z + t1.z + t2.z + t3.z), 1e-12f);
  inv[3] = 1.f / fmaxf(sqrtf(t0.w + t1.w + t2.w + t3.w), 1e-12f);

  const int node0 = blockIdx.x * TN + g * 4;
#pragma unroll
  for (int nt = 0; nt < 4; ++nt) {
    const int n = wv * 64 + nt * 16 + lc;
#pragma unroll
    for (int r = 0; r < 4; ++r) {
      float v = o[nt][r] * inv[r];
      v = (v >= 0.f) ? v : 0.01f * v;
      Hout[(size_t)(node0 + r) * M + n] = f2bf(v);
    }
  }
}

// ---------------- Layer 3: only the 500 readout nodes ----------------

__global__ __launch_bounds__(64) void layer3_kernel(
    const unsigned short* __restrict__ H2,    // [N, 256] bf16
    const int* __restrict__ indptr, const int* __restrict__ srcs,
    const int* __restrict__ first_node,
    const float* __restrict__ W,              // [256, 64] f32
    const float* __restrict__ bias,           // [64] f32
    float* __restrict__ out)                  // [G, 64] f32
{
  __shared__ float a_s[HID_DIM];
  const int g = blockIdx.x;
  const int lane = threadIdx.x;
  const int node = first_node[g];
  float acc[4] = {0.f, 0.f, 0.f, 0.f};
  const int p1 = indptr[node + 1];
  for (int p = indptr[node]; p < p1; ++p) {
    const int s = srcs[p];
    const ushort4 u = *(const ushort4*)(H2 + (size_t)s * HID_DIM + lane * 4);
    acc[0] += bf2f(u.x); acc[1] += bf2f(u.y); acc[2] += bf2f(u.z); acc[3] += bf2f(u.w);
  }
  *(float4*)&a_s[lane * 4] = make_float4(acc[0], acc[1], acc[2], acc[3]);
  __syncthreads();
  float o = bias[lane];
#pragma unroll 8
  for (int k = 0; k < HID_DIM; ++k) o += a_s[k] * W[k * OUT_DIM + lane];
  float ss = o * o;
#pragma unroll
  for (int off = 32; off > 0; off >>= 1) ss += __shfl_xor(ss, off);
  const float inv = 1.f / fmaxf(sqrtf(ss), 1e-12f);
  out[(size_t)g * OUT_DIM + lane] = o * inv;
}

// ---------------- launch ----------------

extern "C" void kernel_launch(void* const* d_in, const int* in_sizes, int n_in,
                              void* d_out, int out_size, void* d_ws, size_t ws_size,
                              hipStream_t stream) {
  (void)in_sizes; (void)n_in; (void)out_size; (void)ws_size;
  const float* x   = (const float*)d_in[0];
  const int* ei    = (const int*)d_in[1];
  const int* batch = (const int*)d_in[2];
  const float* W1  = (const float*)d_in[3];
  const float* b1  = (const float*)d_in[4];
  const float* W2  = (const float*)d_in[5];
  const float* b2  = (const float*)d_in[6];
  const float* W3  = (const float*)d_in[7];
  const float* b3  = (const float*)d_in[8];
  const int* src = ei;
  const int* dst = ei + E_EDGES;

  char* ws = (char*)d_ws;
  size_t off = 0;
  auto alloc = [&](size_t bytes) {
    void* p = ws + off;
    off = (off + bytes + 255) & ~(size_t)255;
    return p;
  };
  int* deg    = (int*)alloc((size_t)N_NODES * 4);
  int* cursor = (int*)alloc((size_t)N_NODES * 4);
  int* indptr = (int*)alloc((size_t)(N_NODES + 1) * 4);
  int* srcs   = (int*)alloc((size_t)(E_EDGES + 64) * 4);   // +64 pad for index window overread
  int* first  = (int*)alloc((size_t)G_GRAPHS * 4);
  unsigned short* W1t = (unsigned short*)alloc((size_t)256 * 128 * 2);
  unsigned short* W2t = (unsigned short*)alloc((size_t)256 * 256 * 2);
  // region: h2 [N,256] bf16; first half doubles as xb [N,128] bf16
  unsigned short* h2 = (unsigned short*)alloc((size_t)N_NODES * HID_DIM * 2);
  unsigned short* xb = h2;
  unsigned short* h1 = (unsigned short*)alloc((size_t)N_NODES * HID_DIM * 2);

  hipMemsetAsync(deg, 0, (size_t)((char*)indptr - (char*)deg), stream);

  count_and_first<<<(E_EDGES + 255) / 256, 256, 0, stream>>>(dst, batch, deg, first);
  scan_indptr<<<1, 1024, 0, stream>>>(deg, indptr);
  fill_csr<<<(E_EDGES + 255) / 256, 256, 0, stream>>>(src, dst, indptr, cursor, srcs);
  conv_x<<<(N_NODES * IN_DIM / 4) / 256, 256, 0, stream>>>(x, xb);
  prep_w<<<512, 64, 0, stream>>>(W1, W2, W1t, W2t);

  // Layer 1: xb bf16 [N,128] -> h1 bf16 [N,256]
  fused_layer<IN_DIM><<<N_NODES / 16, 256, 0, stream>>>(xb, indptr, srcs, W1t, b1, h1);
  // Layer 2: h1 bf16 [N,256] -> h2 bf16 [N,256]
  fused_layer<HID_DIM><<<N_NODES / 16, 256, 0, stream>>>(h1, indptr, srcs, W2t, b2, h2);
  // Layer 3: only the 500 readout nodes -> f32 out
  layer3_kernel<<<G_GRAPHS, 64, 0, stream>>>(h2, indptr, srcs, first, W3, b3, (float*)d_out);
}